// Round 3
// baseline (574.179 us; speedup 1.0000x reference)
//
#include <hip/hip_runtime.h>
#include <cfloat>

#define Bdim 16
#define Vdim 8
#define Sdim 256
#define Kdim 66
#define NSEQ 128                       // B*V sequences
#define TPB 256
#define NROW (Bdim * Sdim * Sdim)      // 1048576 argmax rows
#define ROWS_PER_BLK 128
#define AMAX_BLOCKS (NROW / ROWS_PER_BLK)  // 8192
#define CHUNK 64
#define CHUNK_F (CHUNK * Kdim)         // 4224 floats
#define CHUNK_V4 (CHUNK_F / 4)         // 1056 float4

__device__ __forceinline__ void lds_fence_wave() {
  // single-wave LDS ordering: DS ops from one wave execute in issue order;
  // this only stops the compiler from reordering across it.
  asm volatile("" ::: "memory");
  __builtin_amdgcn_wave_barrier();
  asm volatile("" ::: "memory");
}

__global__ __launch_bounds__(TPB) void crf_fused(
    const float* __restrict__ log_pa,
    const float* __restrict__ score,
    const int*   __restrict__ v_label,
    const int*   __restrict__ orig_l,
    const int*   __restrict__ role_label,
    const float* __restrict__ start_t,
    const float* __restrict__ trans,
    const float* __restrict__ end_t,
    float* __restrict__ out,
    float* __restrict__ ws)
{
  __shared__ __align__(16) float sBuf[2][CHUNK_F];  // 33792 B (argmax aliases both)
  __shared__ __align__(16) float sP[68];
  __shared__ float sGoldW[4];
  __shared__ int   sG[Sdim];

  const int tid = threadIdx.x;
  const int bid = blockIdx.x;

  if (bid >= NSEQ) {
    // ---------------- argmax: 128 rows/block, coalesced float4 staging ----------------
    const int ab = bid - NSEQ;                       // 0..8191
    float* sA = &sBuf[0][0];                         // 8448 floats = 128*66
    const float4* g4 = reinterpret_cast<const float4*>(log_pa + (size_t)ab * ROWS_PER_BLK * Kdim);
    float4* s4 = reinterpret_cast<float4*>(sA);
    for (int f = tid; f < 2 * CHUNK_V4; f += TPB) s4[f] = g4[f];
    __syncthreads();
    if (tid < ROWS_PER_BLK) {
      const float* row = sA + tid * Kdim;
      float best = row[0]; int bi = 0;
#pragma unroll
      for (int e = 1; e < Kdim; ++e) {
        float vv = row[e];
        if (vv > best) { best = vv; bi = e; }
      }
      out[1 + (size_t)ab * ROWS_PER_BLK + tid] = (float)bi;
    }
    return;
  }

  // ---------------- CRF: one block per sequence, probability-space recursion ----------------
  const int n  = bid;
  const int b  = n / Vdim;
  const int v  = n % Vdim;
  const int L  = orig_l[b];                          // 128..256
  const int sl = v_label[b * Vdim + v];
  const float* logits = score + (size_t)(b * Sdim + sl) * Sdim * Kdim;

  // stage chunk 0 + gold labels (all 256 threads)
  {
    float4* dst = reinterpret_cast<float4*>(sBuf[0]);
    const float4* src = reinterpret_cast<const float4*>(logits);
    for (int f = tid; f < CHUNK_V4; f += TPB) dst[f] = src[f];
    sG[tid] = role_label[(size_t)n * Sdim + tid];
  }
  __syncthreads();                                   // chunk 0 + sG visible

  const int lane = tid;                              // valid when tid < 64
  float Ecol[Kdim];                                  // E[i][lane]
  float T64 = 0.f, T65 = 0.f, CA = 0.f, CB = 0.f;
  float q = 0.f, qEx = 0.f, logscale = 0.f;

  if (tid < 64) {
    // wave 0: exp(trans) columns + initial q (overlaps gold below)
#pragma unroll
    for (int i = 0; i < Kdim; ++i) Ecol[i] = __expf(trans[i * Kdim + lane]);
    T64 = __expf(trans[lane * Kdim + 64]);           // E[lane][64]
    T65 = __expf(trans[lane * Kdim + 65]);           // E[lane][65]
    int ex = 64 + (lane & 1);                        // lane0->64, lane1->65 (others unused)
    CA = __expf(trans[ex * Kdim + 64]);              // E[64][64] / E[65][64]
    CB = __expf(trans[ex * Kdim + 65]);              // E[64][65] / E[65][65]
    float a0 = start_t[lane] + sBuf[0][lane];
    float m0 = __shfl(a0, 0, 64);
    q = __expf(a0 - m0);
    if (lane < 2) qEx = __expf(start_t[64 + lane] + sBuf[0][64 + lane] - m0);
    logscale = m0;
  } else {
    // waves 1-3: gold-score partials
    int idx = tid - 64;
    float acc = 0.f;
    for (int t = idx; t < Sdim; t += 192) {
      if (t < L) {
        int g = sG[t];
        float e = logits[t * Kdim + g];
        if (t > 0) e += trans[sG[t - 1] * Kdim + g];
        acc += e;
      }
    }
#pragma unroll
    for (int off = 32; off > 0; off >>= 1) acc += __shfl_xor(acc, off, 64);
    if ((tid & 63) == 0) sGoldW[tid >> 6] = acc;     // slots 1..3
  }

  // chunk loop: waves 1-3 stage chunk c+1 while wave 0 recurses over chunk c
  for (int c = 0; c < 4; ++c) {
    if (tid >= 64) {
      if (c < 3) {
        float4* dst = reinterpret_cast<float4*>(sBuf[(c + 1) & 1]);
        const float4* src = reinterpret_cast<const float4*>(logits + (size_t)(c + 1) * CHUNK_F);
        for (int f = tid - 64; f < CHUNK_V4; f += 192) dst[f] = src[f];
      }
    } else {
      const float* bufc = sBuf[c & 1];
      const int base = c * CHUNK;
      const int t0 = (c == 0) ? 1 : base;
      const int t1 = min(L, base + CHUNK);
      if (t0 < t1) {
        const float4* sP4 = reinterpret_cast<const float4*>(sP);
        float d   = __expf(bufc[(t0 - base) * Kdim + lane]);
        float dEx = (lane < 2) ? __expf(bufc[(t0 - base) * Kdim + 64 + lane]) : 0.f;
        for (int t = t0; t < t1; ++t) {
          // 1. publish q(t)
          sP[lane] = q;
          if (lane < 2) sP[64 + lane] = qEx;
          lds_fence_wave();
          // 2. butterfly for s64/s65 — register inputs, overlaps the broadcast reads
          float a64 = q * T64, a65 = q * T65;
          if (lane < 2) { a64 = fmaf(qEx, CA, a64); a65 = fmaf(qEx, CB, a65); }
          // 3. prefetch next step's d = exp(logit) (off critical path)
          float dn = 0.f, dExn = 0.f;
          if (t + 1 < t1) {
            dn = __expf(bufc[(t + 1 - base) * Kdim + lane]);
            if (lane < 2) dExn = __expf(bufc[(t + 1 - base) * Kdim + 64 + lane]);
          }
#pragma unroll
          for (int off = 32; off > 0; off >>= 1) {
            a64 += __shfl_xor(a64, off, 64);
            a65 += __shfl_xor(a65, off, 64);
          }
          // 4. broadcast reads + 66-FMA dot
          float4 p0 = sP4[0];
          float q0  = p0.x;                          // renorm scale (lane-uniform)
          float inv = __builtin_amdgcn_rcpf(q0);
          float s0 = p0.x * Ecol[0];
          float s1 = p0.y * Ecol[1];
          float s2 = p0.z * Ecol[2];
          float s3 = p0.w * Ecol[3];
#pragma unroll
          for (int qq = 1; qq < 16; ++qq) {
            float4 p = sP4[qq];                      // same-address broadcast, conflict-free
            s0 = fmaf(p.x, Ecol[4 * qq + 0], s0);
            s1 = fmaf(p.y, Ecol[4 * qq + 1], s1);
            s2 = fmaf(p.z, Ecol[4 * qq + 2], s2);
            s3 = fmaf(p.w, Ecol[4 * qq + 3], s3);
          }
          s0 = fmaf(sP[64], Ecol[64], s0);
          s1 = fmaf(sP[65], Ecol[65], s1);
          float dot = (s0 + s1) + (s2 + s3);
          logscale += __logf(q0);                    // off critical path
          q = dot * inv * d;
          if (lane < 2) qEx = ((lane == 0) ? a64 : a65) * inv * dEx;
          d = dn; dEx = dExn;
          lds_fence_wave();                          // keep next writes after these reads
        }
      }
    }
    __syncthreads();                                 // chunk boundary
  }

  // tail: log_z = logscale + log(sum_j q_j * exp(end_j)); gold from sGoldW
  if (tid < 64) {
    float z = q * __expf(end_t[lane]);
    if (lane < 2) z = fmaf(qEx, __expf(end_t[64 + lane]), z);
#pragma unroll
    for (int off = 32; off > 0; off >>= 1) z += __shfl_xor(z, off, 64);
    if (lane == 0) {
      float logz = logscale + __logf(z);
      float gold = sGoldW[1] + sGoldW[2] + sGoldW[3]
                 + start_t[sG[0]] + end_t[sG[L - 1]];
      ws[n] = gold - logz;
    }
  }
}

__global__ void finalize_loss(const float* __restrict__ ws, float* __restrict__ out) {
  __shared__ float r[NSEQ];
  int tid = threadIdx.x;
  r[tid] = ws[tid];
  __syncthreads();
  for (int off = NSEQ / 2; off > 0; off >>= 1) {
    if (tid < off) r[tid] += r[tid + off];
    __syncthreads();
  }
  if (tid == 0) out[0] = r[0] / (float)NSEQ;
}

extern "C" void kernel_launch(void* const* d_in, const int* in_sizes, int n_in,
                              void* d_out, int out_size, void* d_ws, size_t ws_size,
                              hipStream_t stream) {
  const float* log_pa     = (const float*)d_in[0];
  const float* score      = (const float*)d_in[1];
  const int*   v_label    = (const int*)d_in[2];
  // d_in[3] = v_l (unused by reference)
  const int*   orig_l     = (const int*)d_in[4];
  const int*   role_label = (const int*)d_in[5];
  const float* start_t    = (const float*)d_in[6];
  const float* trans      = (const float*)d_in[7];
  const float* end_t      = (const float*)d_in[8];
  float* out = (float*)d_out;
  float* ws  = (float*)d_ws;

  dim3 grid(NSEQ + AMAX_BLOCKS);
  crf_fused<<<grid, TPB, 0, stream>>>(log_pa, score, v_label, orig_l, role_label,
                                      start_t, trans, end_t, out, ws);
  finalize_loss<<<1, NSEQ, 0, stream>>>(ws, out);
}

// Round 4
// 553.871 us; speedup vs baseline: 1.0367x; 1.0367x over previous
//
#include <hip/hip_runtime.h>
#include <cfloat>

#define Bdim 16
#define Vdim 8
#define Sdim 256
#define Kdim 66
#define NSEQ 128                       // B*V sequences
#define TPB 256
#define NROW (Bdim * Sdim * Sdim)      // 1048576 argmax rows
#define ROWS_PER_BLK 128
#define AMAX_BLOCKS (NROW / ROWS_PER_BLK)  // 8192
#define CHUNK 64
#define CHUNK_F (CHUNK * Kdim)         // 4224 floats
#define CHUNK_V4 (CHUNK_F / 4)         // 1056 float4

__device__ __forceinline__ void lds_fence_wave() {
  // single-wave LDS ordering: DS ops from one wave execute in issue order;
  // this only stops the compiler from reordering across it.
  asm volatile("" ::: "memory");
  __builtin_amdgcn_wave_barrier();
  asm volatile("" ::: "memory");
}

// __launch_bounds__(256, 4): 4 wg/CU -> 16 waves/CU -> 128 VGPR budget.
// CRITICAL: without this the allocator caps at ~72 VGPRs and spills the
// 66-entry Ecol[] column to scratch -> ~1800 cyc/step (R3: 194 us).
__global__ __launch_bounds__(TPB, 4) void crf_fused(
    const float* __restrict__ log_pa,
    const float* __restrict__ score,
    const int*   __restrict__ v_label,
    const int*   __restrict__ orig_l,
    const int*   __restrict__ role_label,
    const float* __restrict__ start_t,
    const float* __restrict__ trans,
    const float* __restrict__ end_t,
    float* __restrict__ out,
    float* __restrict__ ws)
{
  __shared__ __align__(16) float sBuf[2][CHUNK_F];  // 33792 B (argmax aliases both)
  __shared__ __align__(16) float sP[68];
  __shared__ float sGoldW[4];
  __shared__ int   sG[Sdim];

  const int tid = threadIdx.x;
  const int bid = blockIdx.x;

  if (bid >= NSEQ) {
    // ---------------- argmax: 128 rows/block, coalesced float4 staging ----------------
    const int ab = bid - NSEQ;                       // 0..8191
    float* sA = &sBuf[0][0];                         // 8448 floats = 128*66
    const float4* g4 = reinterpret_cast<const float4*>(log_pa + (size_t)ab * ROWS_PER_BLK * Kdim);
    float4* s4 = reinterpret_cast<float4*>(sA);
    for (int f = tid; f < 2 * CHUNK_V4; f += TPB) s4[f] = g4[f];
    __syncthreads();
    if (tid < ROWS_PER_BLK) {
      const float2* row2 = reinterpret_cast<const float2*>(sA + tid * Kdim); // 66 even -> aligned
      float best = -FLT_MAX; int bi = 0;
#pragma unroll
      for (int q = 0; q < 33; ++q) {
        float2 v = row2[q];
        if (v.x > best) { best = v.x; bi = 2 * q; }
        if (v.y > best) { best = v.y; bi = 2 * q + 1; }
      }
      out[1 + (size_t)ab * ROWS_PER_BLK + tid] = (float)bi;
    }
    return;
  }

  // ---------------- CRF: one block per sequence, probability-space recursion ----------------
  const int n  = bid;
  const int b  = n / Vdim;
  const int v  = n % Vdim;
  const int L  = orig_l[b];                          // 128..256
  const int sl = v_label[b * Vdim + v];
  const float* logits = score + (size_t)(b * Sdim + sl) * Sdim * Kdim;

  // stage chunk 0 + gold labels (all 256 threads)
  {
    float4* dst = reinterpret_cast<float4*>(sBuf[0]);
    const float4* src = reinterpret_cast<const float4*>(logits);
    for (int f = tid; f < CHUNK_V4; f += TPB) dst[f] = src[f];
    sG[tid] = role_label[(size_t)n * Sdim + tid];
  }
  __syncthreads();                                   // chunk 0 + sG visible

  const int lane = tid;                              // valid when tid < 64
  float Ecol[Kdim];                                  // E[i][lane] — MUST stay in VGPRs
  float T64 = 0.f, T65 = 0.f, CA = 0.f, CB = 0.f;
  float q = 0.f, qEx = 0.f, logscale = 0.f;

  if (tid < 64) {
    // wave 0: exp(trans) columns + initial q (overlaps gold below)
#pragma unroll
    for (int i = 0; i < Kdim; ++i) Ecol[i] = __expf(trans[i * Kdim + lane]);
    T64 = __expf(trans[lane * Kdim + 64]);           // E[lane][64]
    T65 = __expf(trans[lane * Kdim + 65]);           // E[lane][65]
    int ex = 64 + (lane & 1);                        // lane0->64, lane1->65 (others unused)
    CA = __expf(trans[ex * Kdim + 64]);              // E[64][64] / E[65][64]
    CB = __expf(trans[ex * Kdim + 65]);              // E[64][65] / E[65][65]
    float a0 = start_t[lane] + sBuf[0][lane];
    float m0 = __shfl(a0, 0, 64);
    q = __expf(a0 - m0);
    if (lane < 2) qEx = __expf(start_t[64 + lane] + sBuf[0][64 + lane] - m0);
    logscale = m0;
  } else {
    // waves 1-3: gold-score partials
    int idx = tid - 64;
    float acc = 0.f;
    for (int t = idx; t < Sdim; t += 192) {
      if (t < L) {
        int g = sG[t];
        float e = logits[t * Kdim + g];
        if (t > 0) e += trans[sG[t - 1] * Kdim + g];
        acc += e;
      }
    }
#pragma unroll
    for (int off = 32; off > 0; off >>= 1) acc += __shfl_xor(acc, off, 64);
    if ((tid & 63) == 0) sGoldW[tid >> 6] = acc;     // slots 1..3
  }

  // chunk loop: waves 1-3 stage chunk c+1 while wave 0 recurses over chunk c
  for (int c = 0; c < 4; ++c) {
    if (tid >= 64) {
      if (c < 3) {
        float4* dst = reinterpret_cast<float4*>(sBuf[(c + 1) & 1]);
        const float4* src = reinterpret_cast<const float4*>(logits + (size_t)(c + 1) * CHUNK_F);
        for (int f = tid - 64; f < CHUNK_V4; f += 192) dst[f] = src[f];
      }
    } else {
      const float* bufc = sBuf[c & 1];
      const int base = c * CHUNK;
      const int t0 = (c == 0) ? 1 : base;
      const int t1 = min(L, base + CHUNK);
      const float4* sP4 = reinterpret_cast<const float4*>(sP);
      for (int t = t0; t < t1; ++t) {
        const float* rowp = bufc + (t - base) * Kdim;
        // 1. publish q(t)
        sP[lane] = q;
        if (lane < 2) sP[64 + lane] = qEx;
        lds_fence_wave();
        // 2. d = exp(logit row) — LDS read latency hides under the dot
        float d   = __expf(rowp[lane]);
        float dEx = (lane < 2) ? __expf(rowp[64 + lane]) : 0.f;
        // 3. butterfly for s64/s65 — register inputs, overlaps the broadcast reads
        float a64 = q * T64, a65 = q * T65;
        if (lane < 2) { a64 = fmaf(qEx, CA, a64); a65 = fmaf(qEx, CB, a65); }
#pragma unroll
        for (int off = 32; off > 0; off >>= 1) {
          a64 += __shfl_xor(a64, off, 64);
          a65 += __shfl_xor(a65, off, 64);
        }
        // 4. broadcast reads + 66-FMA dot
        float4 p0 = sP4[0];
        float q0  = p0.x;                            // renorm scale (lane-uniform)
        float inv = __builtin_amdgcn_rcpf(q0);
        float s0 = p0.x * Ecol[0];
        float s1 = p0.y * Ecol[1];
        float s2 = p0.z * Ecol[2];
        float s3 = p0.w * Ecol[3];
#pragma unroll
        for (int qq = 1; qq < 16; ++qq) {
          float4 p = sP4[qq];                        // same-address broadcast, conflict-free
          s0 = fmaf(p.x, Ecol[4 * qq + 0], s0);
          s1 = fmaf(p.y, Ecol[4 * qq + 1], s1);
          s2 = fmaf(p.z, Ecol[4 * qq + 2], s2);
          s3 = fmaf(p.w, Ecol[4 * qq + 3], s3);
        }
        s0 = fmaf(sP[64], Ecol[64], s0);
        s1 = fmaf(sP[65], Ecol[65], s1);
        float dot = (s0 + s1) + (s2 + s3);
        logscale += __logf(q0);                      // off critical path
        q = dot * inv * d;
        if (lane < 2) qEx = ((lane == 0) ? a64 : a65) * inv * dEx;
        lds_fence_wave();                            // keep next writes after these reads
      }
    }
    __syncthreads();                                 // chunk boundary
  }

  // tail: log_z = logscale + log(sum_j q_j * exp(end_j)); gold from sGoldW
  if (tid < 64) {
    float z = q * __expf(end_t[lane]);
    if (lane < 2) z = fmaf(qEx, __expf(end_t[64 + lane]), z);
#pragma unroll
    for (int off = 32; off > 0; off >>= 1) z += __shfl_xor(z, off, 64);
    if (lane == 0) {
      float logz = logscale + __logf(z);
      float gold = sGoldW[1] + sGoldW[2] + sGoldW[3]
                 + start_t[sG[0]] + end_t[sG[L - 1]];
      ws[n] = gold - logz;
    }
  }
}

__global__ void finalize_loss(const float* __restrict__ ws, float* __restrict__ out) {
  __shared__ float r[NSEQ];
  int tid = threadIdx.x;
  r[tid] = ws[tid];
  __syncthreads();
  for (int off = NSEQ / 2; off > 0; off >>= 1) {
    if (tid < off) r[tid] += r[tid + off];
    __syncthreads();
  }
  if (tid == 0) out[0] = r[0] / (float)NSEQ;
}

extern "C" void kernel_launch(void* const* d_in, const int* in_sizes, int n_in,
                              void* d_out, int out_size, void* d_ws, size_t ws_size,
                              hipStream_t stream) {
  const float* log_pa     = (const float*)d_in[0];
  const float* score      = (const float*)d_in[1];
  const int*   v_label    = (const int*)d_in[2];
  // d_in[3] = v_l (unused by reference)
  const int*   orig_l     = (const int*)d_in[4];
  const int*   role_label = (const int*)d_in[5];
  const float* start_t    = (const float*)d_in[6];
  const float* trans      = (const float*)d_in[7];
  const float* end_t      = (const float*)d_in[8];
  float* out = (float*)d_out;
  float* ws  = (float*)d_ws;

  dim3 grid(NSEQ + AMAX_BLOCKS);
  crf_fused<<<grid, TPB, 0, stream>>>(log_pa, score, v_label, orig_l, role_label,
                                      start_t, trans, end_t, out, ws);
  finalize_loss<<<1, NSEQ, 0, stream>>>(ws, out);
}

// Round 5
// 547.295 us; speedup vs baseline: 1.0491x; 1.0120x over previous
//
#include <hip/hip_runtime.h>
#include <cfloat>

#define Bdim 16
#define Vdim 8
#define Sdim 256
#define Kdim 66
#define NSEQ 128                       // B*V sequences
#define TPB 256
#define NROW (Bdim * Sdim * Sdim)      // 1048576 argmax rows
#define ROWS_PER_BLK 128
#define AMAX_BLOCKS (NROW / ROWS_PER_BLK)  // 8192
#define CHUNK 64
#define CHUNK_F (CHUNK * Kdim)         // 4224 floats
#define CHUNK_V4 (CHUNK_F / 4)         // 1056 float4

__device__ __forceinline__ void lds_fence_wave() {
  // single-wave LDS ordering: DS ops from one wave execute in issue order;
  // this only stops the compiler from reordering across it.
  asm volatile("" ::: "memory");
  __builtin_amdgcn_wave_barrier();
  asm volatile("" ::: "memory");
}

// __launch_bounds__(256, 2): 2 waves/EU -> 256 VGPR/wave budget.
// CRITICAL history: default (R3) -> 72 VGPR, Ecol spilled to scratch, 194us.
// (256,4) (R4) -> 128 budget split 64 arch + 64 AGPR on gfx950's unified
// file; the 64-arch working set couldn't hold the 16 float4 LDS temps, so
// the 17 broadcast ds_reads serialized at full latency -> 175us. 256 arch
// regs fit Ecol(66) + read temps(64) + state(~40) with room to pipeline.
__global__ __launch_bounds__(TPB, 2) void crf_fused(
    const float* __restrict__ log_pa,
    const float* __restrict__ score,
    const int*   __restrict__ v_label,
    const int*   __restrict__ orig_l,
    const int*   __restrict__ role_label,
    const float* __restrict__ start_t,
    const float* __restrict__ trans,
    const float* __restrict__ end_t,
    float* __restrict__ out,
    float* __restrict__ ws)
{
  __shared__ __align__(16) float sBuf[2][CHUNK_F];  // 33792 B (argmax aliases both)
  __shared__ __align__(16) float sP[68];
  __shared__ float sGoldW[4];
  __shared__ int   sG[Sdim];

  const int tid = threadIdx.x;
  const int bid = blockIdx.x;

  if (bid >= NSEQ) {
    // ---------------- argmax: 128 rows/block, coalesced float4 staging ----------------
    const int ab = bid - NSEQ;                       // 0..8191
    float* sA = &sBuf[0][0];                         // 8448 floats = 128*66
    const float4* g4 = reinterpret_cast<const float4*>(log_pa + (size_t)ab * ROWS_PER_BLK * Kdim);
    float4* s4 = reinterpret_cast<float4*>(sA);
    for (int f = tid; f < 2 * CHUNK_V4; f += TPB) s4[f] = g4[f];
    __syncthreads();
    if (tid < ROWS_PER_BLK) {
      const float2* row2 = reinterpret_cast<const float2*>(sA + tid * Kdim); // 66 even -> aligned
      float best = -FLT_MAX; int bi = 0;
#pragma unroll
      for (int q = 0; q < 33; ++q) {
        float2 v = row2[q];
        if (v.x > best) { best = v.x; bi = 2 * q; }
        if (v.y > best) { best = v.y; bi = 2 * q + 1; }
      }
      out[1 + (size_t)ab * ROWS_PER_BLK + tid] = (float)bi;
    }
    return;
  }

  // ---------------- CRF: one block per sequence, probability-space recursion ----------------
  const int n  = bid;
  const int b  = n / Vdim;
  const int v  = n % Vdim;
  const int L  = orig_l[b];                          // 128..256
  const int sl = v_label[b * Vdim + v];
  const float* logits = score + (size_t)(b * Sdim + sl) * Sdim * Kdim;

  // stage chunk 0 + gold labels (all 256 threads)
  {
    float4* dst = reinterpret_cast<float4*>(sBuf[0]);
    const float4* src = reinterpret_cast<const float4*>(logits);
    for (int f = tid; f < CHUNK_V4; f += TPB) dst[f] = src[f];
    sG[tid] = role_label[(size_t)n * Sdim + tid];
  }
  __syncthreads();                                   // chunk 0 + sG visible

  const int lane = tid;                              // valid when tid < 64
  float Ecol[Kdim];                                  // E[i][lane] — MUST stay in arch VGPRs
  float T64 = 0.f, T65 = 0.f, CA = 0.f, CB = 0.f;
  float q = 0.f, qEx = 0.f, logscale = 0.f;

  if (tid < 64) {
    // wave 0: exp(trans) columns + initial q (overlaps gold below)
#pragma unroll
    for (int i = 0; i < Kdim; ++i) Ecol[i] = __expf(trans[i * Kdim + lane]);
    T64 = __expf(trans[lane * Kdim + 64]);           // E[lane][64]
    T65 = __expf(trans[lane * Kdim + 65]);           // E[lane][65]
    int ex = 64 + (lane & 1);                        // lane0->64, lane1->65 (others unused)
    CA = __expf(trans[ex * Kdim + 64]);              // E[64][64] / E[65][64]
    CB = __expf(trans[ex * Kdim + 65]);              // E[64][65] / E[65][65]
    float a0 = start_t[lane] + sBuf[0][lane];
    float m0 = __shfl(a0, 0, 64);
    q = __expf(a0 - m0);
    if (lane < 2) qEx = __expf(start_t[64 + lane] + sBuf[0][64 + lane] - m0);
    logscale = m0;
  } else {
    // waves 1-3: gold-score partials
    int idx = tid - 64;
    float acc = 0.f;
    for (int t = idx; t < Sdim; t += 192) {
      if (t < L) {
        int g = sG[t];
        float e = logits[t * Kdim + g];
        if (t > 0) e += trans[sG[t - 1] * Kdim + g];
        acc += e;
      }
    }
#pragma unroll
    for (int off = 32; off > 0; off >>= 1) acc += __shfl_xor(acc, off, 64);
    if ((tid & 63) == 0) sGoldW[tid >> 6] = acc;     // slots 1..3
  }

  // chunk loop: waves 1-3 stage chunk c+1 while wave 0 recurses over chunk c
  for (int c = 0; c < 4; ++c) {
    if (tid >= 64) {
      if (c < 3) {
        float4* dst = reinterpret_cast<float4*>(sBuf[(c + 1) & 1]);
        const float4* src = reinterpret_cast<const float4*>(logits + (size_t)(c + 1) * CHUNK_F);
        for (int f = tid - 64; f < CHUNK_V4; f += 192) dst[f] = src[f];
      }
    } else {
      const float* bufc = sBuf[c & 1];
      const int base = c * CHUNK;
      const int t0 = (c == 0) ? 1 : base;
      const int t1 = min(L, base + CHUNK);
      const float4* sP4 = reinterpret_cast<const float4*>(sP);
      for (int t = t0; t < t1; ++t) {
        const float* rowp = bufc + (t - base) * Kdim;
        // 1. publish q(t)
        sP[lane] = q;
        if (lane < 2) sP[64 + lane] = qEx;
        lds_fence_wave();
        // 2. d = exp(logit row) — LDS read latency hides under the dot
        float d   = __expf(rowp[lane]);
        float dEx = (lane < 2) ? __expf(rowp[64 + lane]) : 0.f;
        // 3. butterfly for s64/s65 — register inputs, overlaps the broadcast reads
        float a64 = q * T64, a65 = q * T65;
        if (lane < 2) { a64 = fmaf(qEx, CA, a64); a65 = fmaf(qEx, CB, a65); }
#pragma unroll
        for (int off = 32; off > 0; off >>= 1) {
          a64 += __shfl_xor(a64, off, 64);
          a65 += __shfl_xor(a65, off, 64);
        }
        // 4. broadcast reads + 66-FMA dot (reads pipeline with 256-reg budget)
        float4 p0 = sP4[0];
        float q0  = p0.x;                            // renorm scale (lane-uniform)
        float inv = __builtin_amdgcn_rcpf(q0);
        float s0 = p0.x * Ecol[0];
        float s1 = p0.y * Ecol[1];
        float s2 = p0.z * Ecol[2];
        float s3 = p0.w * Ecol[3];
#pragma unroll
        for (int qq = 1; qq < 16; ++qq) {
          float4 p = sP4[qq];                        // same-address broadcast, conflict-free
          s0 = fmaf(p.x, Ecol[4 * qq + 0], s0);
          s1 = fmaf(p.y, Ecol[4 * qq + 1], s1);
          s2 = fmaf(p.z, Ecol[4 * qq + 2], s2);
          s3 = fmaf(p.w, Ecol[4 * qq + 3], s3);
        }
        s0 = fmaf(sP[64], Ecol[64], s0);
        s1 = fmaf(sP[65], Ecol[65], s1);
        float dot = (s0 + s1) + (s2 + s3);
        logscale += __logf(q0);                      // off critical path
        q = dot * inv * d;
        if (lane < 2) qEx = ((lane == 0) ? a64 : a65) * inv * dEx;
        lds_fence_wave();                            // keep next writes after these reads
      }
    }
    __syncthreads();                                 // chunk boundary
  }

  // tail: log_z = logscale + log(sum_j q_j * exp(end_j)); gold from sGoldW
  if (tid < 64) {
    float z = q * __expf(end_t[lane]);
    if (lane < 2) z = fmaf(qEx, __expf(end_t[64 + lane]), z);
#pragma unroll
    for (int off = 32; off > 0; off >>= 1) z += __shfl_xor(z, off, 64);
    if (lane == 0) {
      float logz = logscale + __logf(z);
      float gold = sGoldW[1] + sGoldW[2] + sGoldW[3]
                 + start_t[sG[0]] + end_t[sG[L - 1]];
      ws[n] = gold - logz;
    }
  }
}

__global__ void finalize_loss(const float* __restrict__ ws, float* __restrict__ out) {
  __shared__ float r[NSEQ];
  int tid = threadIdx.x;
  r[tid] = ws[tid];
  __syncthreads();
  for (int off = NSEQ / 2; off > 0; off >>= 1) {
    if (tid < off) r[tid] += r[tid + off];
    __syncthreads();
  }
  if (tid == 0) out[0] = r[0] / (float)NSEQ;
}

extern "C" void kernel_launch(void* const* d_in, const int* in_sizes, int n_in,
                              void* d_out, int out_size, void* d_ws, size_t ws_size,
                              hipStream_t stream) {
  const float* log_pa     = (const float*)d_in[0];
  const float* score      = (const float*)d_in[1];
  const int*   v_label    = (const int*)d_in[2];
  // d_in[3] = v_l (unused by reference)
  const int*   orig_l     = (const int*)d_in[4];
  const int*   role_label = (const int*)d_in[5];
  const float* start_t    = (const float*)d_in[6];
  const float* trans      = (const float*)d_in[7];
  const float* end_t      = (const float*)d_in[8];
  float* out = (float*)d_out;
  float* ws  = (float*)d_ws;

  dim3 grid(NSEQ + AMAX_BLOCKS);
  crf_fused<<<grid, TPB, 0, stream>>>(log_pa, score, v_label, orig_l, role_label,
                                      start_t, trans, end_t, out, ws);
  finalize_loss<<<1, NSEQ, 0, stream>>>(ws, out);
}